// Round 2
// baseline (428.186 us; speedup 1.0000x reference)
//
#include <hip/hip_runtime.h>
#include <stdint.h>

// Problem: N=8, d=o=16, F=512, NUM_LAYERS=3.  ALL fp32 (per reference).
// out[n,o,g] = LN_o( 0.5*(c1 + c2) )  where
//   c0 = einsum(x, W, A0); h1 = LN_o(c0)
//   c1 = einsum(x, W, A1); c2 = einsum(h1, W, A0)
// einsum(h,W,a)[n,o,g] = sum_{d,f} h[n,d,f] * W[d,f,g,o] * a[f,g]
// W (fp32) is 256 MB -> two streaming passes (c0+c1 share pass 1).

#define F_CHUNK 32
#define N_CHUNKS 16   // 512 / F_CHUNK

// K0: x (fp32, [n][d][f]) -> xT (fp32, [f][d][n])  (65536 elems)
// xT layout makes the inner-loop x operands wave-uniform scalar loads.
__global__ void k0_prep_x(const float* __restrict__ x, float* __restrict__ xT) {
    int idx = blockIdx.x * blockDim.x + threadIdx.x;   // 0..65535
    int n = idx & 7, d = (idx >> 3) & 15, f = idx >> 7;
    xT[idx] = x[n * 8192 + d * 512 + f];
}

// K1 (PASS_A=true):  c0 partials (A[0]) + c1 partials (A[1]) from xT
// K3 (PASS_A=false): c2 partials (A[0]) from xT2 (=h1 transposed)
// grid = (16 f-chunks, 32 col-tiles), block = 256 threads.
// Thread owns one output column (g,o) and all 8 n-accumulators.
// Partial layout: [chunk][g][o][n]  (contiguous 32B per thread -> coalesced)
template <bool PASS_A>
__global__ __launch_bounds__(256)
void k_contract(const float* __restrict__ W, const float* __restrict__ A,
                const float* __restrict__ xT,
                float* __restrict__ p0, float* __restrict__ p1) {
    const int t  = threadIdx.x;
    const int fc = blockIdx.x;                 // 0..15
    const int ct = blockIdx.y;                 // 0..31
    const int g  = ct * 16 + (t >> 4);
    const int o  = t & 15;
    const int col = g * 16 + o;                // 0..8191
    const int f0 = fc * F_CHUNK;

    float c0[8], c1[8];
#pragma unroll
    for (int n = 0; n < 8; ++n) { c0[n] = 0.f; c1[n] = 0.f; }

    const float* Wc = W + col;                 // + d*4194304 + f*8192
    for (int f = f0; f < f0 + F_CHUNK; ++f) {
        // 16 coalesced fp32 loads (wave reads 256B contiguous per d)
        float w[16];
#pragma unroll
        for (int d = 0; d < 16; ++d)
            w[d] = Wc[(size_t)d * 4194304 + (size_t)f * 8192];

        const float* xf = xT + f * 128;        // wave-uniform -> s_load
        float p[8];
#pragma unroll
        for (int n = 0; n < 8; ++n) p[n] = 0.f;
#pragma unroll
        for (int d = 0; d < 16; ++d) {
#pragma unroll
            for (int n = 0; n < 8; ++n)
                p[n] = fmaf(xf[d * 8 + n], w[d], p[n]);
        }

        float a0 = A[f * 512 + g];                       // A[0][f][g]
#pragma unroll
        for (int n = 0; n < 8; ++n) c0[n] = fmaf(a0, p[n], c0[n]);
        if constexpr (PASS_A) {
            float a1 = A[262144 + f * 512 + g];          // A[1][f][g]
#pragma unroll
            for (int n = 0; n < 8; ++n) c1[n] = fmaf(a1, p[n], c1[n]);
        }
    }

    size_t base = (((size_t)fc * 512 + g) * 16 + o) * 8;
#pragma unroll
    for (int n = 0; n < 8; ++n) p0[base + n] = c0[n];
    if constexpr (PASS_A) {
#pragma unroll
        for (int n = 0; n < 8; ++n) p1[base + n] = c1[n];
    }
}

// K2: reduce c0 partials over 16 chunks, LayerNorm over o, write h1 in
// xT-compatible layout: xT2[f=g][d=o][n]  (fp32)
__global__ __launch_bounds__(128)
void k_reduce_ln(const float* __restrict__ part, float* __restrict__ outT) {
    __shared__ float sh[16][8];
    int g = blockIdx.x;                 // 0..511
    int t = threadIdx.x;                // 0..127
    int o = t >> 3, n = t & 7;
    float s = 0.f;
    for (int ch = 0; ch < 16; ++ch)
        s += part[(((size_t)ch * 512 + g) * 16 + o) * 8 + n];
    sh[o][n] = s;
    __syncthreads();
    float m = 0.f, v = 0.f;
#pragma unroll
    for (int oo = 0; oo < 16; ++oo) { float y = sh[oo][n]; m += y; v += y * y; }
    m *= (1.f / 16.f);
    v = v * (1.f / 16.f) - m * m;
    float r = rsqrtf(v + 1e-5f);
    outT[((size_t)g * 16 + o) * 8 + n] = (s - m) * r;
}

// K4: y = 0.5*(c1+c2) (reduced over chunks), LayerNorm over o, fp32 out [n][o][g]
__global__ __launch_bounds__(128)
void k_final(const float* __restrict__ p1, const float* __restrict__ p2,
             float* __restrict__ out) {
    __shared__ float sh[16][8];
    int g = blockIdx.x;
    int t = threadIdx.x;
    int o = t >> 3, n = t & 7;
    float s = 0.f;
    for (int ch = 0; ch < 16; ++ch) {
        size_t idx = (((size_t)ch * 512 + g) * 16 + o) * 8 + n;
        s += p1[idx] + p2[idx];
    }
    s *= 0.5f;
    sh[o][n] = s;
    __syncthreads();
    float m = 0.f, v = 0.f;
#pragma unroll
    for (int oo = 0; oo < 16; ++oo) { float y = sh[oo][n]; m += y; v += y * y; }
    m *= (1.f / 16.f);
    v = v * (1.f / 16.f) - m * m;
    float r = rsqrtf(v + 1e-5f);
    out[n * 8192 + o * 512 + g] = (s - m) * r;
}

extern "C" void kernel_launch(void* const* d_in, const int* in_sizes, int n_in,
                              void* d_out, int out_size, void* d_ws, size_t ws_size,
                              hipStream_t stream) {
    const float* x = (const float*)d_in[0];   // (8,16,512)      fp32
    const float* W = (const float*)d_in[1];   // (16,512,512,16) fp32
    const float* A = (const float*)d_in[2];   // (2,512,512)     fp32
    float* out = (float*)d_out;               // (8,16,512)      fp32

    float* ws  = (float*)d_ws;
    float* xT  = ws;                    //   65536 floats: x  transposed [f][d][n]
    float* xT2 = ws + 65536;            //   65536 floats: h1 transposed [f][d][n]
    float* c0p = ws + 131072;           // 1048576 floats: c0 partials [16][512][16][8]
    float* c1p = c0p + 1048576;         // 1048576 floats: c1 partials
    float* c2p = c1p + 1048576;         // 1048576 floats: c2 partials
    // total ws use: 12.5 MB

    k0_prep_x<<<256, 256, 0, stream>>>(x, xT);
    k_contract<true ><<<dim3(N_CHUNKS, 32), 256, 0, stream>>>(W, A, xT,  c0p, c1p);
    k_reduce_ln<<<512, 128, 0, stream>>>(c0p, xT2);
    k_contract<false><<<dim3(N_CHUNKS, 32), 256, 0, stream>>>(W, A, xT2, c2p, nullptr);
    k_final<<<512, 128, 0, stream>>>(c1p, c2p, out);
}